// Round 6
// baseline (344.940 us; speedup 1.0000x reference)
//
#include <hip/hip_runtime.h>
#include <hip/hip_fp16.h>
#include <math.h>

// Problem constants (fixed by reference)
#define Z 2
#define NPT 256     // points per batch
#define CHN 16      // channels
#define NH 2        // heads
#define NBK 10      // key/conv radial basis
#define HD 100      // radial hidden width
#define NBV 3       // value radial basis
#define G 512       // radial table grid points (L2-resident)
// Unified table domain [0, VD]. Key/conv radials are exactly 0 beyond
// 5+5/9 (all cosine bases zero); value radial support extends to 7.5.
// At d = VD all three radials are exactly 0, so the gi>=G-1 clamp is exact.
#define VD 7.5f

__device__ __forceinline__ float swishf(float x) {
    return x / (1.0f + __expf(-x));
}

// dot of 8 fp16 table elements (one uint4) with 8 fp32 features
__device__ __forceinline__ float dot8(uint4 u, float4 a, float4 b) {
    float2 c0 = __half22float2(*(const __half2*)&u.x);
    float2 c1 = __half22float2(*(const __half2*)&u.y);
    float2 c2 = __half22float2(*(const __half2*)&u.z);
    float2 c3 = __half22float2(*(const __half2*)&u.w);
    return c0.x*a.x + c0.y*a.y + c1.x*a.z + c1.y*a.w
         + c2.x*b.x + c2.y*b.y + c3.x*b.z + c3.y*b.w;
}

// ---------------------------------------------------------------------------
// Kernel 1 (merged): proven radial-MLP evaluation (verbatim compute from the
// verified build_tables) + in-block fold of the final linear layer (pattern
// proven in build_mats), writing fp16 swizzled matrix tables directly.
//   K heads -> MKV[h][g][0..255]   (swizzled 16x16)
//   V heads -> MKV[h][g][256..511]
//   conv    -> MC[g][0..255]
// Swizzle within a 256-half region: element (i,j) -> (c*16+i)*8 + (j&7),
// c=j>>3, so consumer lane i's chunk-c uint4 load is 256B contiguous.
// reps: 0,1 = key heads (2-layer); 2 = conv (2-layer); 3,4 = value (1-layer).
// 16 grid pts per block; grid = 5*32 = 160 blocks x 128 threads.
// Block 0 also zeroes d_out so conv can atomicAdd.
// ---------------------------------------------------------------------------
__global__ __launch_bounds__(128)
void build_all(const float* __restrict__ K0, const float* __restrict__ K1,
               const float* __restrict__ Kf,
               const float* __restrict__ C0, const float* __restrict__ C1,
               const float* __restrict__ Cf,
               const float* __restrict__ V0, const float* __restrict__ Vf,
               __half* __restrict__ MKV, __half* __restrict__ MC,
               float* __restrict__ out_zero) {
    int bid = blockIdx.x;
    int rep = bid >> 5;              // 0..4
    int g0  = (bid & 31) * 16;
    int t   = threadIdx.x;

    if (bid == 0) {                  // zero d_out: Z*NPT*CHN = 8192 floats
        float4* o4 = (float4*)out_zero;
        #pragma unroll
        for (int k = 0; k < 16; ++k) o4[k*128 + t] = make_float4(0.f,0.f,0.f,0.f);
    }

    __shared__ float s_b10[16][NBK];
    __shared__ __align__(16) float s_h1[HD*16];   // [n][k]
    __shared__ float s_h2[16][HD];                // h(g)[m] staged for fold

    if (rep >= 3) {                  // value heads: 1-layer radial (proven)
        const float* W0v = V0 + (rep - 3)*NBV*HD;
        if (t < HD) {
            #pragma unroll
            for (int k = 0; k < 16; ++k) {
                int gg = g0 + k;
                float d = gg * (VD / (float)(G-1));
                float s = 0.f;
                #pragma unroll
                for (int q = 0; q < NBV; ++q) {
                    float diff = (d - q*2.5f) * 0.4f;
                    float bq = (fabsf(diff) < 1.0f) ? __cosf(1.57079632679f*diff) : 0.f;
                    s += bq * W0v[q*HD + t];
                }
                s_h2[k][t] = swishf(s);
            }
        }
    } else {                         // 2-layer radial (proven compute)
        const float* W0 = (rep == 0) ? K0 : (rep == 1) ? (K0 + NBK*HD) : C0;
        const float* W1 = (rep == 0) ? K1 : (rep == 1) ? (K1 + HD*HD)  : C1;

        if (t < 16) {
            float d = (g0 + t) * (VD / (float)(G-1));
            #pragma unroll
            for (int q = 0; q < NBK; ++q) {
                float diff = (d - q*(5.0f/9.0f)) * 1.8f;
                s_b10[t][q] = (fabsf(diff) < 1.0f) ? __cosf(1.57079632679f*diff) : 0.f;
            }
        }
        __syncthreads();
        if (t < HD) {
            int n = t;
            float w[NBK];
            #pragma unroll
            for (int q = 0; q < NBK; ++q) w[q] = W0[q*HD + n];
            #pragma unroll
            for (int k = 0; k < 16; ++k) {
                float s = 0.f;
                #pragma unroll
                for (int q = 0; q < NBK; ++q) s += s_b10[k][q] * w[q];
                s_h1[n*16 + k] = swishf(s);
            }
        }
        __syncthreads();
        if (t < HD) {
            int m = t;
            float acc[16];
            #pragma unroll
            for (int k = 0; k < 16; ++k) acc[k] = 0.f;
            const float* w1 = W1 + m;
            #pragma unroll 2
            for (int n = 0; n < HD; ++n) {
                float w = w1[n*HD];                            // coalesced
                const float4* hp = (const float4*)&s_h1[n*16]; // broadcast
                float4 x0 = hp[0], x1 = hp[1], x2 = hp[2], x3 = hp[3];
                acc[0]+=x0.x*w;  acc[1]+=x0.y*w;  acc[2]+=x0.z*w;  acc[3]+=x0.w*w;
                acc[4]+=x1.x*w;  acc[5]+=x1.y*w;  acc[6]+=x1.z*w;  acc[7]+=x1.w*w;
                acc[8]+=x2.x*w;  acc[9]+=x2.y*w;  acc[10]+=x2.z*w; acc[11]+=x2.w*w;
                acc[12]+=x3.x*w; acc[13]+=x3.y*w; acc[14]+=x3.z*w; acc[15]+=x3.w*w;
            }
            #pragma unroll
            for (int k = 0; k < 16; ++k) s_h2[k][m] = swishf(acc[k]);
        }
    }
    __syncthreads();

    // fold final linear layer (proven math): M[g][e] = sum_m h2[g][m]*Wf[m][e]
    const float* Wf = (rep == 0) ? Kf
                    : (rep == 1) ? (Kf + HD*256)
                    : (rep == 2) ? Cf
                    : (rep == 3) ? Vf : (Vf + HD*256);
    __half* dst  = (rep == 2) ? MC  : (MKV + (size_t)((rep == 1 || rep == 4) ? 1 : 0)*G*512);
    int    voff  = (rep >= 3) ? 256 : 0;
    int    strd  = (rep == 2) ? 256 : 512;

    for (int eb = 0; eb < 2; ++eb) {
        int e = t + eb*128;
        float facc[16];
        #pragma unroll
        for (int gp = 0; gp < 16; ++gp) facc[gp] = 0.f;
        for (int m = 0; m < HD; ++m) {
            float w = Wf[m*256 + e];                 // coalesced over t
            #pragma unroll
            for (int gp = 0; gp < 16; ++gp) facc[gp] += s_h2[gp][m] * w;
        }
        int i = e >> 4, j = e & 15, c = j >> 3, eo = j & 7;
        size_t off = (size_t)(c*16 + i)*8 + eo;      // swizzled within region
        #pragma unroll
        for (int gp = 0; gp < 16; ++gp)
            dst[(size_t)(g0+gp)*strd + voff + off] = __float2half(facc[gp]);
    }
}

// ---------------------------------------------------------------------------
// Kernel 2 (single-pass): fused scores + softmax + value. One block per
// (z,h,a) = 1024 blocks x 256 threads (16 groups of 16 lanes). Lane i owns
// matrix row i. Per (group,b): 8 uint4 loads from the interleaved MKV table
// (K rows g,g+1 and V rows g,g+1 -> 2KB contiguous); computes the score AND
// the lerped value-row dot yv in one pass; yv parked in registers so phase D
// needs no table traffic at all.
// ---------------------------------------------------------------------------
__global__ __launch_bounds__(256, 4)
void fused_attn(const float* __restrict__ f, const float* __restrict__ xyz,
                const float* __restrict__ Wq,
                const __half* __restrict__ MKV,
                float* __restrict__ attn_h) {
    int bid = blockIdx.x;            // (z*NH + h)*NPT + a
    int a  = bid & 255;
    int zh = bid >> 8;
    int h  = zh & 1;
    int z  = zh >> 1;
    int t  = threadIdx.x;

    __shared__ __align__(16) float s_f[NPT*CHN];   // 16384 B
    __shared__ int   s_gi[NPT];
    __shared__ float s_fr[NPT];
    __shared__ float s_sc[NPT];                    // scores then p
    __shared__ float s_q[16];
    __shared__ float s_red[8];
    __shared__ float s_red2[256];

    // stage features + per-b geometry (proven)
    {
        const float4* fz = (const float4*)(f + (size_t)z*NPT*CHN);
        float4* sf = (float4*)s_f;
        for (int idx = t; idx < NPT*CHN/4; idx += 256) sf[idx] = fz[idx];
    }
    {
        float ax = xyz[(z*NPT + a)*3 + 0];
        float ay = xyz[(z*NPT + a)*3 + 1];
        float az = xyz[(z*NPT + a)*3 + 2];
        int b = t;
        float dx = xyz[(z*NPT + b)*3 + 0] - ax;
        float dy = xyz[(z*NPT + b)*3 + 1] - ay;
        float dz = xyz[(z*NPT + b)*3 + 2] - az;
        float d = sqrtf(dx*dx + dy*dy + dz*dz + 1e-12f);
        float fd = d * ((float)(G-1) / VD);
        int   gi = (int)fd;
        float fr = fd - (float)gi;
        if (gi >= G-1) { gi = G-2; fr = 1.0f; }    // beyond support -> exact 0
        s_gi[b] = gi; s_fr[b] = fr;
    }
    __syncthreads();
    if (t < CHN) {       // q[o] = sum_i f[a,i] * Wq[h][o][i]
        float s = 0.f;
        const float* wq = Wq + (h*CHN + t)*CHN;
        for (int i = 0; i < CHN; ++i) s += s_f[a*CHN + i] * wq[i];
        s_q[t] = s;
    }
    __syncthreads();

    int Gr = t >> 4;     // group 0..15
    int i  = t & 15;     // matrix row owned by this lane
    float qi = s_q[i];
    int b0 = Gr*16;

    float yv[16];        // fully unrolled -> stays in VGPRs (rule #20)

    // single pass: scores + value dots
    {
        const __half* base = MKV + (size_t)h*G*512;
        #pragma unroll
        for (int k = 0; k < 16; ++k) {
            int b = b0 + k;
            const uint4* p = (const uint4*)(base + (size_t)s_gi[b]*512) + i;
            uint4 k0 = p[0],  k1 = p[16];    // K row gi   (j 0..7 | 8..15)
            uint4 v0 = p[32], v1 = p[48];    // V row gi
            uint4 k2 = p[64], k3 = p[80];    // K row gi+1
            uint4 v2 = p[96], v3 = p[112];   // V row gi+1
            float fr = s_fr[b];
            const float4* fp = (const float4*)&s_f[b*CHN];
            float4 f0=fp[0], f1=fp[1], f2=fp[2], f3=fp[3];
            float yk0 = dot8(k0, f0, f1) + dot8(k1, f2, f3);
            float yk1 = dot8(k2, f0, f1) + dot8(k3, f2, f3);
            float sc = qi * (yk0 + fr*(yk1 - yk0));
            sc += __shfl_xor(sc, 1);
            sc += __shfl_xor(sc, 2);
            sc += __shfl_xor(sc, 4);
            sc += __shfl_xor(sc, 8);
            if (i == 0) s_sc[b] = sc * (1.0f/16.0f);
            float w0 = dot8(v0, f0, f1) + dot8(v1, f2, f3);
            float w1 = dot8(v2, f0, f1) + dot8(v3, f2, f3);
            yv[k] = w0 + fr*(w1 - w0);
        }
    }
    __syncthreads();

    // softmax over 256 scores (verified code)
    {
        float v = s_sc[t];
        float mx = v;
        for (int off = 32; off >= 1; off >>= 1) mx = fmaxf(mx, __shfl_xor(mx, off));
        int wid = t >> 6;
        if ((t & 63) == 0) s_red[wid] = mx;
        __syncthreads();
        mx = fmaxf(fmaxf(s_red[0], s_red[1]), fmaxf(s_red[2], s_red[3]));
        float e = __expf(v - mx);
        float s = e;
        for (int off = 32; off >= 1; off >>= 1) s += __shfl_xor(s, off);
        if ((t & 63) == 0) s_red[4 + wid] = s;
        __syncthreads();
        float tot = s_red[4] + s_red[5] + s_red[6] + s_red[7];
        s_sc[t] = e / tot;
    }
    __syncthreads();

    // weighted sum from registers: out[i] = sum_k p[b0+k] * yv[k]
    {
        float o = 0.f;
        #pragma unroll
        for (int k = 0; k < 16; ++k) o += s_sc[b0 + k] * yv[k];
        s_red2[Gr*16 + i] = o;
    }
    __syncthreads();
    if (t < 16) {
        float s = 0.f;
        for (int gp = 0; gp < 16; ++gp) s += s_red2[gp*16 + t];
        attn_h[(size_t)bid*CHN + t] = s;
    }
}

// ---------------------------------------------------------------------------
// Kernel 3 (VERBATIM round-5, proven): final conv via folded MC table.
// One block per (z,a,b-half) = 1024 blocks. atomicAdd (out zeroed by build).
// ---------------------------------------------------------------------------
__global__ __launch_bounds__(256)
void conv_kernel(const float* __restrict__ xyz, const __half* __restrict__ MC,
                 const float* __restrict__ attn_h, float* __restrict__ out) {
    int bid = blockIdx.x;
    int bh  = bid & 1;
    int za  = bid >> 1;
    int z   = za >> 8;
    int b0g = bh * 128;
    int t   = threadIdx.x;

    __shared__ __align__(16) float s_ao[128*CHN];  // head-summed attn output
    __shared__ int   s_gi[128];
    __shared__ float s_fr[128];
    __shared__ float s_red2[256];

    for (int idx = t; idx < 128*CHN; idx += 256) {
        s_ao[idx] = attn_h[(size_t)(z*NH + 0)*NPT*CHN + b0g*CHN + idx]
                  + attn_h[(size_t)(z*NH + 1)*NPT*CHN + b0g*CHN + idx];
    }
    if (t < 128) {
        int b = b0g + t;
        float dx = xyz[(z*NPT+b)*3+0] - xyz[za*3+0];
        float dy = xyz[(z*NPT+b)*3+1] - xyz[za*3+1];
        float dz = xyz[(z*NPT+b)*3+2] - xyz[za*3+2];
        float d = sqrtf(dx*dx + dy*dy + dz*dz + 1e-12f);
        float fd = d * ((float)(G-1) / VD);
        int   gi = (int)fd;
        float fr = fd - (float)gi;
        if (gi >= G-1) { gi = G-2; fr = 1.0f; }
        s_gi[t] = gi; s_fr[t] = fr;
    }
    __syncthreads();

    int Gr = t >> 4;     // group 0..15, 8 local b's each
    int i  = t & 15;     // matrix row owned by this lane
    int l0 = Gr*8;
    {
        float o = 0.f;
        for (int k = 0; k < 8; ++k) {
            int l = l0 + k;
            const uint4* p = (const uint4*)(MC + (size_t)s_gi[l]*256) + i;
            uint4 q0 = p[0];
            uint4 q1 = p[16];
            uint4 q2 = p[32];
            uint4 q3 = p[48];
            float fr = s_fr[l];
            const float4* ap = (const float4*)&s_ao[l*CHN];
            float4 a0=ap[0], a1=ap[1], a2=ap[2], a3=ap[3];
            float y0 = dot8(q0, a0, a1) + dot8(q1, a2, a3);
            float y1 = dot8(q2, a0, a1) + dot8(q3, a2, a3);
            o += y0 + fr*(y1 - y0);
        }
        s_red2[Gr*16 + i] = o;
    }
    __syncthreads();
    if (t < 16) {
        float s = 0.f;
        for (int gp = 0; gp < 16; ++gp) s += s_red2[gp*16 + t];
        atomicAdd(out + (size_t)za*CHN + t, s);
    }
}

// ---------------------------------------------------------------------------
extern "C" void kernel_launch(void* const* d_in, const int* in_sizes, int n_in,
                              void* d_out, int out_size, void* d_ws, size_t ws_size,
                              hipStream_t stream) {
    const float* f   = (const float*)d_in[0];
    const float* xyz = (const float*)d_in[1];
    const float* Wq  = (const float*)d_in[2];
    const float* K0  = (const float*)d_in[3];
    const float* K1  = (const float*)d_in[4];
    const float* Kf  = (const float*)d_in[5];
    const float* V0  = (const float*)d_in[6];
    const float* Vf  = (const float*)d_in[7];
    const float* C0  = (const float*)d_in[8];
    const float* C1  = (const float*)d_in[9];
    const float* Cf  = (const float*)d_in[10];
    float* out = (float*)d_out;

    // workspace: MKV[h][g][512] (K|V fp16 swizzled) | MC[g][256] | attn_h
    __half* MKV    = (__half*)d_ws;
    __half* MC     = MKV + (size_t)NH*G*512;
    float*  attn_h = (float*)(MC + (size_t)G*256);

    build_all  <<<160,      128, 0, stream>>>(K0, K1, Kf, C0, C1, Cf, V0, Vf,
                                              MKV, MC, out);
    fused_attn <<<Z*NH*NPT, 256, 0, stream>>>(f, xyz, Wq, MKV, attn_h);
    conv_kernel<<<Z*NPT*2,  256, 0, stream>>>(xyz, MC, attn_h, out);
}

// Round 7
// 138.519 us; speedup vs baseline: 2.4902x; 2.4902x over previous
//
#include <hip/hip_runtime.h>
#include <hip/hip_fp16.h>
#include <math.h>

// Problem constants (fixed by reference)
#define Z 2
#define NPT 256     // points per batch
#define CHN 16      // channels
#define NH 2        // heads
#define NBK 10      // key/conv radial basis
#define HD 100      // radial hidden width
#define NBV 3       // value radial basis
#define G 512       // radial table grid points (L2-resident)
// Unified table domain [0, VD]. Key/conv radials are exactly 0 beyond
// 5+5/9 (all cosine bases zero); value radial support extends to 7.5.
// At d = VD all three radials are exactly 0, so the gi>=G-1 clamp is exact.
#define VD 7.5f

__device__ __forceinline__ float swishf(float x) {
    return x / (1.0f + __expf(-x));
}

// dot of 8 fp16 table elements (one uint4) with 8 fp32 features
__device__ __forceinline__ float dot8(uint4 u, float4 a, float4 b) {
    float2 c0 = __half22float2(*(const __half2*)&u.x);
    float2 c1 = __half22float2(*(const __half2*)&u.y);
    float2 c2 = __half22float2(*(const __half2*)&u.z);
    float2 c3 = __half22float2(*(const __half2*)&u.w);
    return c0.x*a.x + c0.y*a.y + c1.x*a.z + c1.y*a.w
         + c2.x*b.x + c2.y*b.y + c3.x*b.z + c3.y*b.w;
}

// ---------------------------------------------------------------------------
// Kernel 1 (VERBATIM round-6, proven): radial-MLP evaluation + in-block fold
// of the final linear layer, writing fp16 swizzled matrix tables directly.
//   K heads -> MKV[h][g][0..255]   (swizzled 16x16)
//   V heads -> MKV[h][g][256..511]
//   conv    -> MC[g][0..255]
// Swizzle within a 256-half region: element (i,j) -> (c*16+i)*8 + (j&7),
// c=j>>3, so consumer lane i's chunk-c uint4 load is 256B contiguous.
// reps: 0,1 = key heads (2-layer); 2 = conv (2-layer); 3,4 = value (1-layer).
// 16 grid pts per block; grid = 5*32 = 160 blocks x 128 threads.
// Block 0 also zeroes d_out so conv can atomicAdd.
// ---------------------------------------------------------------------------
__global__ __launch_bounds__(128)
void build_all(const float* __restrict__ K0, const float* __restrict__ K1,
               const float* __restrict__ Kf,
               const float* __restrict__ C0, const float* __restrict__ C1,
               const float* __restrict__ Cf,
               const float* __restrict__ V0, const float* __restrict__ Vf,
               __half* __restrict__ MKV, __half* __restrict__ MC,
               float* __restrict__ out_zero) {
    int bid = blockIdx.x;
    int rep = bid >> 5;              // 0..4
    int g0  = (bid & 31) * 16;
    int t   = threadIdx.x;

    if (bid == 0) {                  // zero d_out: Z*NPT*CHN = 8192 floats
        float4* o4 = (float4*)out_zero;
        #pragma unroll
        for (int k = 0; k < 16; ++k) o4[k*128 + t] = make_float4(0.f,0.f,0.f,0.f);
    }

    __shared__ float s_b10[16][NBK];
    __shared__ __align__(16) float s_h1[HD*16];   // [n][k]
    __shared__ float s_h2[16][HD];                // h(g)[m] staged for fold

    if (rep >= 3) {                  // value heads: 1-layer radial (proven)
        const float* W0v = V0 + (rep - 3)*NBV*HD;
        if (t < HD) {
            #pragma unroll
            for (int k = 0; k < 16; ++k) {
                int gg = g0 + k;
                float d = gg * (VD / (float)(G-1));
                float s = 0.f;
                #pragma unroll
                for (int q = 0; q < NBV; ++q) {
                    float diff = (d - q*2.5f) * 0.4f;
                    float bq = (fabsf(diff) < 1.0f) ? __cosf(1.57079632679f*diff) : 0.f;
                    s += bq * W0v[q*HD + t];
                }
                s_h2[k][t] = swishf(s);
            }
        }
    } else {                         // 2-layer radial (proven compute)
        const float* W0 = (rep == 0) ? K0 : (rep == 1) ? (K0 + NBK*HD) : C0;
        const float* W1 = (rep == 0) ? K1 : (rep == 1) ? (K1 + HD*HD)  : C1;

        if (t < 16) {
            float d = (g0 + t) * (VD / (float)(G-1));
            #pragma unroll
            for (int q = 0; q < NBK; ++q) {
                float diff = (d - q*(5.0f/9.0f)) * 1.8f;
                s_b10[t][q] = (fabsf(diff) < 1.0f) ? __cosf(1.57079632679f*diff) : 0.f;
            }
        }
        __syncthreads();
        if (t < HD) {
            int n = t;
            float w[NBK];
            #pragma unroll
            for (int q = 0; q < NBK; ++q) w[q] = W0[q*HD + n];
            #pragma unroll
            for (int k = 0; k < 16; ++k) {
                float s = 0.f;
                #pragma unroll
                for (int q = 0; q < NBK; ++q) s += s_b10[k][q] * w[q];
                s_h1[n*16 + k] = swishf(s);
            }
        }
        __syncthreads();
        if (t < HD) {
            int m = t;
            float acc[16];
            #pragma unroll
            for (int k = 0; k < 16; ++k) acc[k] = 0.f;
            const float* w1 = W1 + m;
            #pragma unroll 2
            for (int n = 0; n < HD; ++n) {
                float w = w1[n*HD];                            // coalesced
                const float4* hp = (const float4*)&s_h1[n*16]; // broadcast
                float4 x0 = hp[0], x1 = hp[1], x2 = hp[2], x3 = hp[3];
                acc[0]+=x0.x*w;  acc[1]+=x0.y*w;  acc[2]+=x0.z*w;  acc[3]+=x0.w*w;
                acc[4]+=x1.x*w;  acc[5]+=x1.y*w;  acc[6]+=x1.z*w;  acc[7]+=x1.w*w;
                acc[8]+=x2.x*w;  acc[9]+=x2.y*w;  acc[10]+=x2.z*w; acc[11]+=x2.w*w;
                acc[12]+=x3.x*w; acc[13]+=x3.y*w; acc[14]+=x3.z*w; acc[15]+=x3.w*w;
            }
            #pragma unroll
            for (int k = 0; k < 16; ++k) s_h2[k][m] = swishf(acc[k]);
        }
    }
    __syncthreads();

    // fold final linear layer (proven math): M[g][e] = sum_m h2[g][m]*Wf[m][e]
    const float* Wf = (rep == 0) ? Kf
                    : (rep == 1) ? (Kf + HD*256)
                    : (rep == 2) ? Cf
                    : (rep == 3) ? Vf : (Vf + HD*256);
    __half* dst  = (rep == 2) ? MC  : (MKV + (size_t)((rep == 1 || rep == 4) ? 1 : 0)*G*512);
    int    voff  = (rep >= 3) ? 256 : 0;
    int    strd  = (rep == 2) ? 256 : 512;

    for (int eb = 0; eb < 2; ++eb) {
        int e = t + eb*128;
        float facc[16];
        #pragma unroll
        for (int gp = 0; gp < 16; ++gp) facc[gp] = 0.f;
        for (int m = 0; m < HD; ++m) {
            float w = Wf[m*256 + e];                 // coalesced over t
            #pragma unroll
            for (int gp = 0; gp < 16; ++gp) facc[gp] += s_h2[gp][m] * w;
        }
        int i = e >> 4, j = e & 15, c = j >> 3, eo = j & 7;
        size_t off = (size_t)(c*16 + i)*8 + eo;      // swizzled within region
        #pragma unroll
        for (int gp = 0; gp < 16; ++gp)
            dst[(size_t)(g0+gp)*strd + voff + off] = __float2half(facc[gp]);
    }
}

// ---------------------------------------------------------------------------
// Kernel 2 (single-pass, spill-fixed): fused scores + softmax + value.
// One block per (z,h,a) = 1024 blocks x 256 threads (16 groups of 16 lanes).
// Lane i owns matrix row i. Per (group,b): 8 uint4 loads from interleaved
// MKV (2KB contiguous); score AND lerped value dot computed in one pass.
// yv lives in LDS (not registers) so the k-loop can be partially unrolled
// without spilling (round-6 lesson: full unroll + reg yv -> 443MB scratch).
// ---------------------------------------------------------------------------
__global__ __launch_bounds__(256, 4)
void fused_attn(const float* __restrict__ f, const float* __restrict__ xyz,
                const float* __restrict__ Wq,
                const __half* __restrict__ MKV,
                float* __restrict__ attn_h) {
    int bid = blockIdx.x;            // (z*NH + h)*NPT + a
    int a  = bid & 255;
    int zh = bid >> 8;
    int h  = zh & 1;
    int z  = zh >> 1;
    int t  = threadIdx.x;

    __shared__ __align__(16) float s_f[NPT*CHN];   // 16384 B
    __shared__ float s_yv[NPT*16];                 // 16384 B  yv[b][i]
    __shared__ int   s_gi[NPT];
    __shared__ float s_fr[NPT];
    __shared__ float s_sc[NPT];                    // scores then p
    __shared__ float s_q[16];
    __shared__ float s_red[8];
    __shared__ float s_red2[256];

    // stage features + per-b geometry (proven)
    {
        const float4* fz = (const float4*)(f + (size_t)z*NPT*CHN);
        float4* sf = (float4*)s_f;
        for (int idx = t; idx < NPT*CHN/4; idx += 256) sf[idx] = fz[idx];
    }
    {
        float ax = xyz[(z*NPT + a)*3 + 0];
        float ay = xyz[(z*NPT + a)*3 + 1];
        float az = xyz[(z*NPT + a)*3 + 2];
        int b = t;
        float dx = xyz[(z*NPT + b)*3 + 0] - ax;
        float dy = xyz[(z*NPT + b)*3 + 1] - ay;
        float dz = xyz[(z*NPT + b)*3 + 2] - az;
        float d = sqrtf(dx*dx + dy*dy + dz*dz + 1e-12f);
        float fd = d * ((float)(G-1) / VD);
        int   gi = (int)fd;
        float fr = fd - (float)gi;
        if (gi >= G-1) { gi = G-2; fr = 1.0f; }    // beyond support -> exact 0
        s_gi[b] = gi; s_fr[b] = fr;
    }
    __syncthreads();
    if (t < CHN) {       // q[o] = sum_i f[a,i] * Wq[h][o][i]
        float s = 0.f;
        const float* wq = Wq + (h*CHN + t)*CHN;
        for (int i = 0; i < CHN; ++i) s += s_f[a*CHN + i] * wq[i];
        s_q[t] = s;
    }
    __syncthreads();

    int Gr = t >> 4;     // group 0..15
    int i  = t & 15;     // matrix row owned by this lane
    float qi = s_q[i];
    int b0 = Gr*16;

    // single pass: scores + value dots (yv -> LDS, modest unroll: no spill)
    {
        const __half* base = MKV + (size_t)h*G*512;
        #pragma unroll 2
        for (int k = 0; k < 16; ++k) {
            int b = b0 + k;
            const uint4* p = (const uint4*)(base + (size_t)s_gi[b]*512) + i;
            uint4 k0 = p[0],  k1 = p[16];    // K row gi   (j 0..7 | 8..15)
            uint4 v0 = p[32], v1 = p[48];    // V row gi
            uint4 k2 = p[64], k3 = p[80];    // K row gi+1
            uint4 v2 = p[96], v3 = p[112];   // V row gi+1
            float fr = s_fr[b];
            const float4* fp = (const float4*)&s_f[b*CHN];
            float4 f0=fp[0], f1=fp[1], f2=fp[2], f3=fp[3];
            float yk0 = dot8(k0, f0, f1) + dot8(k1, f2, f3);
            float yk1 = dot8(k2, f0, f1) + dot8(k3, f2, f3);
            float sc = qi * (yk0 + fr*(yk1 - yk0));
            sc += __shfl_xor(sc, 1);
            sc += __shfl_xor(sc, 2);
            sc += __shfl_xor(sc, 4);
            sc += __shfl_xor(sc, 8);
            if (i == 0) s_sc[b] = sc * (1.0f/16.0f);
            float w0 = dot8(v0, f0, f1) + dot8(v1, f2, f3);
            float w1 = dot8(v2, f0, f1) + dot8(v3, f2, f3);
            s_yv[b*16 + i] = w0 + fr*(w1 - w0);
        }
    }
    __syncthreads();

    // softmax over 256 scores (verified code)
    {
        float v = s_sc[t];
        float mx = v;
        for (int off = 32; off >= 1; off >>= 1) mx = fmaxf(mx, __shfl_xor(mx, off));
        int wid = t >> 6;
        if ((t & 63) == 0) s_red[wid] = mx;
        __syncthreads();
        mx = fmaxf(fmaxf(s_red[0], s_red[1]), fmaxf(s_red[2], s_red[3]));
        float e = __expf(v - mx);
        float s = e;
        for (int off = 32; off >= 1; off >>= 1) s += __shfl_xor(s, off);
        if ((t & 63) == 0) s_red[4 + wid] = s;
        __syncthreads();
        float tot = s_red[4] + s_red[5] + s_red[6] + s_red[7];
        s_sc[t] = e / tot;
    }
    __syncthreads();

    // weighted sum from LDS: out[i] = sum_k p[b0+k] * yv[b0+k][i]
    {
        float o = 0.f;
        #pragma unroll
        for (int k = 0; k < 16; ++k) o += s_sc[b0 + k] * s_yv[(b0 + k)*16 + i];
        s_red2[Gr*16 + i] = o;
    }
    __syncthreads();
    if (t < 16) {
        float s = 0.f;
        for (int gp = 0; gp < 16; ++gp) s += s_red2[gp*16 + t];
        attn_h[(size_t)bid*CHN + t] = s;
    }
}

// ---------------------------------------------------------------------------
// Kernel 3 (VERBATIM, proven): final conv via folded MC table.
// One block per (z,a,b-half) = 1024 blocks. atomicAdd (out zeroed by build).
// ---------------------------------------------------------------------------
__global__ __launch_bounds__(256)
void conv_kernel(const float* __restrict__ xyz, const __half* __restrict__ MC,
                 const float* __restrict__ attn_h, float* __restrict__ out) {
    int bid = blockIdx.x;
    int bh  = bid & 1;
    int za  = bid >> 1;
    int z   = za >> 8;
    int b0g = bh * 128;
    int t   = threadIdx.x;

    __shared__ __align__(16) float s_ao[128*CHN];  // head-summed attn output
    __shared__ int   s_gi[128];
    __shared__ float s_fr[128];
    __shared__ float s_red2[256];

    for (int idx = t; idx < 128*CHN; idx += 256) {
        s_ao[idx] = attn_h[(size_t)(z*NH + 0)*NPT*CHN + b0g*CHN + idx]
                  + attn_h[(size_t)(z*NH + 1)*NPT*CHN + b0g*CHN + idx];
    }
    if (t < 128) {
        int b = b0g + t;
        float dx = xyz[(z*NPT+b)*3+0] - xyz[za*3+0];
        float dy = xyz[(z*NPT+b)*3+1] - xyz[za*3+1];
        float dz = xyz[(z*NPT+b)*3+2] - xyz[za*3+2];
        float d = sqrtf(dx*dx + dy*dy + dz*dz + 1e-12f);
        float fd = d * ((float)(G-1) / VD);
        int   gi = (int)fd;
        float fr = fd - (float)gi;
        if (gi >= G-1) { gi = G-2; fr = 1.0f; }
        s_gi[t] = gi; s_fr[t] = fr;
    }
    __syncthreads();

    int Gr = t >> 4;     // group 0..15, 8 local b's each
    int i  = t & 15;     // matrix row owned by this lane
    int l0 = Gr*8;
    {
        float o = 0.f;
        for (int k = 0; k < 8; ++k) {
            int l = l0 + k;
            const uint4* p = (const uint4*)(MC + (size_t)s_gi[l]*256) + i;
            uint4 q0 = p[0];
            uint4 q1 = p[16];
            uint4 q2 = p[32];
            uint4 q3 = p[48];
            float fr = s_fr[l];
            const float4* ap = (const float4*)&s_ao[l*CHN];
            float4 a0=ap[0], a1=ap[1], a2=ap[2], a3=ap[3];
            float y0 = dot8(q0, a0, a1) + dot8(q1, a2, a3);
            float y1 = dot8(q2, a0, a1) + dot8(q3, a2, a3);
            o += y0 + fr*(y1 - y0);
        }
        s_red2[Gr*16 + i] = o;
    }
    __syncthreads();
    if (t < 16) {
        float s = 0.f;
        for (int gp = 0; gp < 16; ++gp) s += s_red2[gp*16 + t];
        atomicAdd(out + (size_t)za*CHN + t, s);
    }
}

// ---------------------------------------------------------------------------
extern "C" void kernel_launch(void* const* d_in, const int* in_sizes, int n_in,
                              void* d_out, int out_size, void* d_ws, size_t ws_size,
                              hipStream_t stream) {
    const float* f   = (const float*)d_in[0];
    const float* xyz = (const float*)d_in[1];
    const float* Wq  = (const float*)d_in[2];
    const float* K0  = (const float*)d_in[3];
    const float* K1  = (const float*)d_in[4];
    const float* Kf  = (const float*)d_in[5];
    const float* V0  = (const float*)d_in[6];
    const float* Vf  = (const float*)d_in[7];
    const float* C0  = (const float*)d_in[8];
    const float* C1  = (const float*)d_in[9];
    const float* Cf  = (const float*)d_in[10];
    float* out = (float*)d_out;

    // workspace: MKV[h][g][512] (K|V fp16 swizzled) | MC[g][256] | attn_h
    __half* MKV    = (__half*)d_ws;
    __half* MC     = MKV + (size_t)NH*G*512;
    float*  attn_h = (float*)(MC + (size_t)G*256);

    build_all  <<<160,      128, 0, stream>>>(K0, K1, Kf, C0, C1, Cf, V0, Vf,
                                              MKV, MC, out);
    fused_attn <<<Z*NH*NPT, 256, 0, stream>>>(f, xyz, Wq, MKV, attn_h);
    conv_kernel<<<Z*NPT*2,  256, 0, stream>>>(xyz, MC, attn_h, out);
}

// Round 8
// 132.453 us; speedup vs baseline: 2.6042x; 1.0458x over previous
//
#include <hip/hip_runtime.h>
#include <hip/hip_fp16.h>
#include <math.h>

// Problem constants (fixed by reference)
#define Z 2
#define NPT 256     // points per batch
#define CHN 16      // channels
#define NH 2        // heads
#define NBK 10      // key/conv radial basis
#define HD 100      // radial hidden width
#define NBV 3       // value radial basis
#define G 512       // radial table grid points (L2-resident)
// Unified table domain [0, VD]. Key/conv radials are exactly 0 beyond
// 5+5/9 (all cosine bases zero); value radial support extends to 7.5.
// At d = VD all three radials are exactly 0, so the gi>=G-1 clamp is exact.
#define VD 7.5f

__device__ __forceinline__ float swishf(float x) {
    return x / (1.0f + __expf(-x));
}

// dot of 8 fp16 table elements (one uint4) with 8 fp32 features
__device__ __forceinline__ float dot8(uint4 u, float4 a, float4 b) {
    float2 c0 = __half22float2(*(const __half2*)&u.x);
    float2 c1 = __half22float2(*(const __half2*)&u.y);
    float2 c2 = __half22float2(*(const __half2*)&u.z);
    float2 c3 = __half22float2(*(const __half2*)&u.w);
    return c0.x*a.x + c0.y*a.y + c1.x*a.z + c1.y*a.w
         + c2.x*b.x + c2.y*b.y + c3.x*b.z + c3.y*b.w;
}

// ---------------------------------------------------------------------------
// Kernel 1 (VERBATIM, proven x3): build radial activation tables as
// interleaved float2 {T[g], T[g+1]}; also zeroes d_out (block 0).
// reps: 0,1 = key heads (2-layer); 2 = conv (2-layer); 3,4 = value (1-layer).
// 16 grid pts per block; grid = 5*32 = 160 blocks x 128 threads.
// ---------------------------------------------------------------------------
__global__ __launch_bounds__(128)
void build_tables(const float* __restrict__ K0, const float* __restrict__ K1,
                  const float* __restrict__ C0, const float* __restrict__ C1,
                  const float* __restrict__ V0,
                  float* __restrict__ TKf, float* __restrict__ TCf,
                  float* __restrict__ TVf, float* __restrict__ out_zero) {
    int bid = blockIdx.x;
    int rep = bid >> 5;              // 0..4
    int g0  = (bid & 31) * 16;
    int t   = threadIdx.x;

    if (bid == 0) {                  // zero d_out: Z*NPT*CHN = 8192 floats
        float4* o4 = (float4*)out_zero;
        #pragma unroll
        for (int k = 0; k < 16; ++k) o4[k*128 + t] = make_float4(0.f,0.f,0.f,0.f);
    }

    if (rep >= 3) {                  // value heads: 1-layer radial
        const float* W0v = V0 + (rep - 3)*NBV*HD;
        float* Tf = TVf + (size_t)(rep - 3)*2*G*HD;
        if (t < HD) {
            #pragma unroll
            for (int k = 0; k < 16; ++k) {
                int gg = g0 + k;
                float d = gg * (VD / (float)(G-1));
                float s = 0.f;
                #pragma unroll
                for (int q = 0; q < NBV; ++q) {
                    float diff = (d - q*2.5f) * 0.4f;
                    float bq = (fabsf(diff) < 1.0f) ? __cosf(1.57079632679f*diff) : 0.f;
                    s += bq * W0v[q*HD + t];
                }
                float v = swishf(s);
                Tf[2*((size_t)gg*HD + t) + 0] = v;
                if (gg > 0) Tf[2*((size_t)(gg-1)*HD + t) + 1] = v;
            }
        }
        return;
    }

    const float* W0 = (rep == 0) ? K0 : (rep == 1) ? (K0 + NBK*HD) : C0;
    const float* W1 = (rep == 0) ? K1 : (rep == 1) ? (K1 + HD*HD)  : C1;
    float* Tf       = (rep == 0) ? TKf : (rep == 1) ? (TKf + 2*(size_t)G*HD) : TCf;

    __shared__ float s_b10[16][NBK];
    __shared__ __align__(16) float s_h1[HD*16];   // [n][k]

    if (t < 16) {
        float d = (g0 + t) * (VD / (float)(G-1));
        #pragma unroll
        for (int q = 0; q < NBK; ++q) {
            float diff = (d - q*(5.0f/9.0f)) * 1.8f;
            s_b10[t][q] = (fabsf(diff) < 1.0f) ? __cosf(1.57079632679f*diff) : 0.f;
        }
    }
    __syncthreads();
    if (t < HD) {
        int n = t;
        float w[NBK];
        #pragma unroll
        for (int q = 0; q < NBK; ++q) w[q] = W0[q*HD + n];
        #pragma unroll
        for (int k = 0; k < 16; ++k) {
            float s = 0.f;
            #pragma unroll
            for (int q = 0; q < NBK; ++q) s += s_b10[k][q] * w[q];
            s_h1[n*16 + k] = swishf(s);
        }
    }
    __syncthreads();
    if (t < HD) {
        int m = t;
        float acc[16];
        #pragma unroll
        for (int k = 0; k < 16; ++k) acc[k] = 0.f;
        const float* w1 = W1 + m;
        #pragma unroll 2
        for (int n = 0; n < HD; ++n) {
            float w = w1[n*HD];                            // coalesced across m
            const float4* hp = (const float4*)&s_h1[n*16]; // broadcast
            float4 x0 = hp[0], x1 = hp[1], x2 = hp[2], x3 = hp[3];
            acc[0]+=x0.x*w;  acc[1]+=x0.y*w;  acc[2]+=x0.z*w;  acc[3]+=x0.w*w;
            acc[4]+=x1.x*w;  acc[5]+=x1.y*w;  acc[6]+=x1.z*w;  acc[7]+=x1.w*w;
            acc[8]+=x2.x*w;  acc[9]+=x2.y*w;  acc[10]+=x2.z*w; acc[11]+=x2.w*w;
            acc[12]+=x3.x*w; acc[13]+=x3.y*w; acc[14]+=x3.z*w; acc[15]+=x3.w*w;
        }
        #pragma unroll
        for (int k = 0; k < 16; ++k) {
            float v = swishf(acc[k]);
            int gg = g0 + k;
            Tf[2*((size_t)gg*HD + m) + 0] = v;
            if (gg > 0) Tf[2*((size_t)(gg-1)*HD + m) + 1] = v;
        }
    }
}

// ---------------------------------------------------------------------------
// Kernel 1b (round-5 proven structure; round-7 proven dst layout): fold the
// final linear layers into per-grid-point 16x16 fp16 matrices, swizzled.
//   K heads -> MKV[h][g][0..255] ; V heads -> MKV[h][g][256..511]
//   conv    -> MC[g][0..255]
// Swizzle within a 256-half region: element (i,j) -> (c*16+i)*8 + (j&7),
// c=j>>3, so consumer lane i's chunk-c uint4 load is 256B contiguous.
// 4 g's per block; grid = 5*128 = 640 blocks x 256 threads.
// ---------------------------------------------------------------------------
__global__ __launch_bounds__(256)
void build_mats(const float* __restrict__ TK, const float* __restrict__ TC,
                const float* __restrict__ TV,
                const float* __restrict__ Kf, const float* __restrict__ Cf,
                const float* __restrict__ Vf,
                __half* __restrict__ MKV, __half* __restrict__ MC) {
    int bid = blockIdx.x;
    int rep = bid >> 7;              // 0..4
    int g0  = (bid & 127) * 4;
    int t   = threadIdx.x;

    const float *T, *Wf;
    if (rep == 0)      { T=TK;                    Wf=Kf;          }
    else if (rep == 1) { T=TK+2*(size_t)G*HD;     Wf=Kf+HD*256;   }
    else if (rep == 2) { T=TC;                    Wf=Cf;          }
    else if (rep == 3) { T=TV;                    Wf=Vf;          }
    else               { T=TV+2*(size_t)G*HD;     Wf=Vf+HD*256;   }
    __half* dst = (rep == 2) ? MC
                : (MKV + (size_t)((rep == 1 || rep == 4) ? 1 : 0)*G*512);
    int voff = (rep >= 3) ? 256 : 0;
    int strd = (rep == 2) ? 256 : 512;

    __shared__ float s_h[4][HD];
    for (int idx = t; idx < 4*HD; idx += 256) {
        int gp = idx / HD, m = idx - gp*HD;
        s_h[gp][m] = T[2*((size_t)(g0+gp)*HD + m)];   // slot 0
    }
    __syncthreads();

    float a0=0.f, a1=0.f, a2=0.f, a3=0.f;
    for (int m = 0; m < HD; ++m) {
        float w = Wf[m*256 + t];                      // coalesced over t
        a0 += s_h[0][m]*w; a1 += s_h[1][m]*w;
        a2 += s_h[2][m]*w; a3 += s_h[3][m]*w;
    }
    int i = t >> 4, j = t & 15, c = j >> 3, eo = j & 7;
    size_t off = (size_t)(c*16 + i)*8 + eo;           // swizzled within region
    dst[(size_t)(g0+0)*strd + voff + off] = __float2half(a0);
    dst[(size_t)(g0+1)*strd + voff + off] = __float2half(a1);
    dst[(size_t)(g0+2)*strd + voff + off] = __float2half(a2);
    dst[(size_t)(g0+3)*strd + voff + off] = __float2half(a3);
}

// ---------------------------------------------------------------------------
// Kernel 2 (VERBATIM round-7, proven): single-pass fused scores + softmax +
// value. One block per (z,h,a) = 1024 blocks x 256 threads (16 groups of 16
// lanes). Lane i owns matrix row i. Per (group,b): 8 uint4 loads from the
// interleaved MKV (2KB contiguous); yv in LDS; partial unroll (no spill).
// ---------------------------------------------------------------------------
__global__ __launch_bounds__(256, 4)
void fused_attn(const float* __restrict__ f, const float* __restrict__ xyz,
                const float* __restrict__ Wq,
                const __half* __restrict__ MKV,
                float* __restrict__ attn_h) {
    int bid = blockIdx.x;            // (z*NH + h)*NPT + a
    int a  = bid & 255;
    int zh = bid >> 8;
    int h  = zh & 1;
    int z  = zh >> 1;
    int t  = threadIdx.x;

    __shared__ __align__(16) float s_f[NPT*CHN];   // 16384 B
    __shared__ float s_yv[NPT*16];                 // 16384 B  yv[b][i]
    __shared__ int   s_gi[NPT];
    __shared__ float s_fr[NPT];
    __shared__ float s_sc[NPT];                    // scores then p
    __shared__ float s_q[16];
    __shared__ float s_red[8];
    __shared__ float s_red2[256];

    // stage features + per-b geometry (proven)
    {
        const float4* fz = (const float4*)(f + (size_t)z*NPT*CHN);
        float4* sf = (float4*)s_f;
        for (int idx = t; idx < NPT*CHN/4; idx += 256) sf[idx] = fz[idx];
    }
    {
        float ax = xyz[(z*NPT + a)*3 + 0];
        float ay = xyz[(z*NPT + a)*3 + 1];
        float az = xyz[(z*NPT + a)*3 + 2];
        int b = t;
        float dx = xyz[(z*NPT + b)*3 + 0] - ax;
        float dy = xyz[(z*NPT + b)*3 + 1] - ay;
        float dz = xyz[(z*NPT + b)*3 + 2] - az;
        float d = sqrtf(dx*dx + dy*dy + dz*dz + 1e-12f);
        float fd = d * ((float)(G-1) / VD);
        int   gi = (int)fd;
        float fr = fd - (float)gi;
        if (gi >= G-1) { gi = G-2; fr = 1.0f; }    // beyond support -> exact 0
        s_gi[b] = gi; s_fr[b] = fr;
    }
    __syncthreads();
    if (t < CHN) {       // q[o] = sum_i f[a,i] * Wq[h][o][i]
        float s = 0.f;
        const float* wq = Wq + (h*CHN + t)*CHN;
        for (int i = 0; i < CHN; ++i) s += s_f[a*CHN + i] * wq[i];
        s_q[t] = s;
    }
    __syncthreads();

    int Gr = t >> 4;     // group 0..15
    int i  = t & 15;     // matrix row owned by this lane
    float qi = s_q[i];
    int b0 = Gr*16;

    // single pass: scores + value dots (yv -> LDS, modest unroll: no spill)
    {
        const __half* base = MKV + (size_t)h*G*512;
        #pragma unroll 2
        for (int k = 0; k < 16; ++k) {
            int b = b0 + k;
            const uint4* p = (const uint4*)(base + (size_t)s_gi[b]*512) + i;
            uint4 k0 = p[0],  k1 = p[16];    // K row gi   (j 0..7 | 8..15)
            uint4 v0 = p[32], v1 = p[48];    // V row gi
            uint4 k2 = p[64], k3 = p[80];    // K row gi+1
            uint4 v2 = p[96], v3 = p[112];   // V row gi+1
            float fr = s_fr[b];
            const float4* fp = (const float4*)&s_f[b*CHN];
            float4 f0=fp[0], f1=fp[1], f2=fp[2], f3=fp[3];
            float yk0 = dot8(k0, f0, f1) + dot8(k1, f2, f3);
            float yk1 = dot8(k2, f0, f1) + dot8(k3, f2, f3);
            float sc = qi * (yk0 + fr*(yk1 - yk0));
            sc += __shfl_xor(sc, 1);
            sc += __shfl_xor(sc, 2);
            sc += __shfl_xor(sc, 4);
            sc += __shfl_xor(sc, 8);
            if (i == 0) s_sc[b] = sc * (1.0f/16.0f);
            float w0 = dot8(v0, f0, f1) + dot8(v1, f2, f3);
            float w1 = dot8(v2, f0, f1) + dot8(v3, f2, f3);
            s_yv[b*16 + i] = w0 + fr*(w1 - w0);
        }
    }
    __syncthreads();

    // softmax over 256 scores (verified code)
    {
        float v = s_sc[t];
        float mx = v;
        for (int off = 32; off >= 1; off >>= 1) mx = fmaxf(mx, __shfl_xor(mx, off));
        int wid = t >> 6;
        if ((t & 63) == 0) s_red[wid] = mx;
        __syncthreads();
        mx = fmaxf(fmaxf(s_red[0], s_red[1]), fmaxf(s_red[2], s_red[3]));
        float e = __expf(v - mx);
        float s = e;
        for (int off = 32; off >= 1; off >>= 1) s += __shfl_xor(s, off);
        if ((t & 63) == 0) s_red[4 + wid] = s;
        __syncthreads();
        float tot = s_red[4] + s_red[5] + s_red[6] + s_red[7];
        s_sc[t] = e / tot;
    }
    __syncthreads();

    // weighted sum from LDS: out[i] = sum_k p[b0+k] * yv[b0+k][i]
    {
        float o = 0.f;
        #pragma unroll
        for (int k = 0; k < 16; ++k) o += s_sc[b0 + k] * s_yv[(b0 + k)*16 + i];
        s_red2[Gr*16 + i] = o;
    }
    __syncthreads();
    if (t < 16) {
        float s = 0.f;
        for (int gp = 0; gp < 16; ++gp) s += s_red2[gp*16 + t];
        attn_h[(size_t)bid*CHN + t] = s;
    }
}

// ---------------------------------------------------------------------------
// Kernel 3 (VERBATIM, proven x4): final conv via folded MC table.
// One block per (z,a,b-half) = 1024 blocks. atomicAdd (out zeroed by build).
// ---------------------------------------------------------------------------
__global__ __launch_bounds__(256)
void conv_kernel(const float* __restrict__ xyz, const __half* __restrict__ MC,
                 const float* __restrict__ attn_h, float* __restrict__ out) {
    int bid = blockIdx.x;
    int bh  = bid & 1;
    int za  = bid >> 1;
    int z   = za >> 8;
    int b0g = bh * 128;
    int t   = threadIdx.x;

    __shared__ __align__(16) float s_ao[128*CHN];  // head-summed attn output
    __shared__ int   s_gi[128];
    __shared__ float s_fr[128];
    __shared__ float s_red2[256];

    for (int idx = t; idx < 128*CHN; idx += 256) {
        s_ao[idx] = attn_h[(size_t)(z*NH + 0)*NPT*CHN + b0g*CHN + idx]
                  + attn_h[(size_t)(z*NH + 1)*NPT*CHN + b0g*CHN + idx];
    }
    if (t < 128) {
        int b = b0g + t;
        float dx = xyz[(z*NPT+b)*3+0] - xyz[za*3+0];
        float dy = xyz[(z*NPT+b)*3+1] - xyz[za*3+1];
        float dz = xyz[(z*NPT+b)*3+2] - xyz[za*3+2];
        float d = sqrtf(dx*dx + dy*dy + dz*dz + 1e-12f);
        float fd = d * ((float)(G-1) / VD);
        int   gi = (int)fd;
        float fr = fd - (float)gi;
        if (gi >= G-1) { gi = G-2; fr = 1.0f; }
        s_gi[t] = gi; s_fr[t] = fr;
    }
    __syncthreads();

    int Gr = t >> 4;     // group 0..15, 8 local b's each
    int i  = t & 15;     // matrix row owned by this lane
    int l0 = Gr*8;
    {
        float o = 0.f;
        for (int k = 0; k < 8; ++k) {
            int l = l0 + k;
            const uint4* p = (const uint4*)(MC + (size_t)s_gi[l]*256) + i;
            uint4 q0 = p[0];
            uint4 q1 = p[16];
            uint4 q2 = p[32];
            uint4 q3 = p[48];
            float fr = s_fr[l];
            const float4* ap = (const float4*)&s_ao[l*CHN];
            float4 a0=ap[0], a1=ap[1], a2=ap[2], a3=ap[3];
            float y0 = dot8(q0, a0, a1) + dot8(q1, a2, a3);
            float y1 = dot8(q2, a0, a1) + dot8(q3, a2, a3);
            o += y0 + fr*(y1 - y0);
        }
        s_red2[Gr*16 + i] = o;
    }
    __syncthreads();
    if (t < 16) {
        float s = 0.f;
        for (int gp = 0; gp < 16; ++gp) s += s_red2[gp*16 + t];
        atomicAdd(out + (size_t)za*CHN + t, s);
    }
}

// ---------------------------------------------------------------------------
extern "C" void kernel_launch(void* const* d_in, const int* in_sizes, int n_in,
                              void* d_out, int out_size, void* d_ws, size_t ws_size,
                              hipStream_t stream) {
    const float* f   = (const float*)d_in[0];
    const float* xyz = (const float*)d_in[1];
    const float* Wq  = (const float*)d_in[2];
    const float* K0  = (const float*)d_in[3];
    const float* K1  = (const float*)d_in[4];
    const float* Kf  = (const float*)d_in[5];
    const float* V0  = (const float*)d_in[6];
    const float* Vf  = (const float*)d_in[7];
    const float* C0  = (const float*)d_in[8];
    const float* C1  = (const float*)d_in[9];
    const float* Cf  = (const float*)d_in[10];
    float* out = (float*)d_out;

    // workspace: TK2 | TC2 | TV2 (fp32 activation tables) |
    //            MKV[h][g][512] (K|V fp16 swizzled) | MC | attn_h
    float2* TK2    = (float2*)d_ws;
    float2* TC2    = TK2 + (size_t)NH*G*HD;
    float2* TV2    = TC2 + (size_t)G*HD;
    __half* MKV    = (__half*)(TV2 + (size_t)NH*G*HD);
    __half* MC     = MKV + (size_t)NH*G*512;
    float*  attn_h = (float*)(MC + (size_t)G*256);

    build_tables<<<160,      128, 0, stream>>>(K0, K1, C0, C1, V0,
                                               (float*)TK2, (float*)TC2,
                                               (float*)TV2, out);
    build_mats  <<<640,      256, 0, stream>>>((const float*)TK2, (const float*)TC2,
                                               (const float*)TV2, Kf, Cf, Vf,
                                               MKV, MC);
    fused_attn  <<<Z*NH*NPT, 256, 0, stream>>>(f, xyz, Wq, MKV, attn_h);
    conv_kernel <<<Z*NPT*2,  256, 0, stream>>>(xyz, MC, attn_h, out);
}